// Round 1
// baseline (3681.194 us; speedup 1.0000x reference)
//
#include <hip/hip_runtime.h>

#define BB 256
#define TT 2048
#define SS 32
#define NN 19
#define NCLASS 10
#define NUNFOLD 6
#define EPSV 1e-8f
#define LOG2E 1.4426950408889634f

// ---------------------------------------------------------------------------
// Phase 1: sensory synapse precompute.
// thread = (t, b, j): num/den over s=0..31, written to sens[t][b][0..18]=num,
// sens[t][b][19..37]=den.  Input-only dependence -> fully parallel.
// ---------------------------------------------------------------------------
__global__ void ltc_sens_kernel(const float* __restrict__ x,
                                const float* __restrict__ iw,
                                const float* __restrict__ ib,
                                const float* __restrict__ smu,
                                const float* __restrict__ ssig,
                                const float* __restrict__ sw,
                                const float* __restrict__ serev,
                                const int* __restrict__ smask,
                                float* __restrict__ sens,
                                int t0, int tc)
{
    int gid = blockIdx.x * blockDim.x + threadIdx.x;
    int total = tc * BB * NN;
    if (gid >= total) return;
    int j  = gid % NN;
    int tb = gid / NN;
    int b  = tb % BB;
    int tl = tb / BB;
    int t  = t0 + tl;

    const float* xr = x + ((long)b * TT + t) * SS;
    // vectorized x row load (32 floats = 8 x float4)
    float xin[SS];
    const float4* xr4 = (const float4*)xr;
#pragma unroll
    for (int q = 0; q < SS / 4; q++) {
        float4 v4 = xr4[q];
        xin[4 * q + 0] = v4.x; xin[4 * q + 1] = v4.y;
        xin[4 * q + 2] = v4.z; xin[4 * q + 3] = v4.w;
    }

    float num = 0.f, den = 0.f;
#pragma unroll
    for (int s = 0; s < SS; s++) {
        float inp = fmaf(xin[s], iw[s], ib[s]);      // map_inputs
        int idx = s * NN + j;
        float sg = ssig[idx];
        // sigmoid(sg*(inp-mu)) = 1/(1+exp2(-log2e*sg*(inp-mu)))
        float e  = __builtin_amdgcn_exp2f(fmaf(-LOG2E * sg, inp, LOG2E * sg * smu[idx]));
        float sig = __builtin_amdgcn_rcpf(1.0f + e);
        float wm = sw[idx] * (float)smask[idx] * sig;
        num = fmaf(wm, serev[idx], num);
        den += wm;
    }
    float* o = sens + ((long)tl * BB + b) * (2 * NN);
    o[j]      = num;
    o[NN + j] = den;
}

// ---------------------------------------------------------------------------
// Phase 2: the sequential scan.  One wave (64 threads) per batch element.
// Lane layout: lane = 3*j + r  (j=0..18 post-neuron, r=0..2 pre-neuron chunk).
// r==0 -> i in [0,7), r==1 -> i in [7,13), r==2 -> i in [13,19).
// Leader lane (r==0) owns v[j].  v[i] fetched via ds_bpermute from lane 3*i.
// ---------------------------------------------------------------------------
__global__ void __launch_bounds__(64, 1)
ltc_scan_kernel(const float* __restrict__ mu,  const float* __restrict__ sigma,
                const float* __restrict__ w,   const float* __restrict__ erev,
                const int* __restrict__ mask,
                const float* __restrict__ gleak, const float* __restrict__ vleak,
                const float* __restrict__ cm,
                const float* __restrict__ ow,  const float* __restrict__ ob,
                const float* __restrict__ sens, float* __restrict__ outbuf,
                float* __restrict__ vstate, int t0, int tc, int initv)
{
    int b    = blockIdx.x;
    int lane = threadIdx.x;
    int j = lane / 3; if (j > NN - 1) j = NN - 1;
    int r = lane - 3 * j;                       // lanes 57..63: j=18, r>=3 (dummy)
    bool leader = (r == 0) && (lane < 3 * NN);

    int i0  = (r == 0) ? 0 : (r == 1) ? 7 : 13;
    int cnt = (lane >= 3 * NN) ? 0 : ((r == 0) ? 7 : 6);

    // per-lane folded constants for my pre-neuron chunk
    float sg2[7], sb2[7], Aa[7], Wm[7];
    int src4[7];
#pragma unroll
    for (int k = 0; k < 7; k++) {
        bool ok = (k < cnt);
        int ii = ok ? (i0 + k) : 0;
        int idx = ii * NN + j;
        float sg = sigma[idx];
        float wmm = ok ? (w[idx] * (float)mask[idx]) : 0.f;
        sg2[k] = -LOG2E * sg;
        sb2[k] = LOG2E * sg * mu[idx];
        Aa[k]  = wmm * erev[idx];
        Wm[k]  = wmm;
        src4[k] = (3 * ii) << 2;                // ds_bpermute byte addr of leader lane
    }
    float cmt  = cm[j] * (float)NUNFOLD;
    float gl   = gleak[j];
    float glvl = gl * vleak[j];
    float ow0 = ow[0], ob0 = ob[0];

    int rp1 = (lane + 1) << 2;                  // reduction shuffle addrs
    int rp2 = (lane + 2) << 2;

    float v = initv ? 0.f : vstate[b * NN + j];

    const float* sp0 = sens + ((long)0 * BB + b) * (2 * NN);
    float sn = sp0[j];
    float sd = sp0[NN + j];

    for (int t = 0; t < tc; t++) {
        // prefetch next step's sensory sums (latency hidden by 6 unfolds)
        float sn_nx = sn, sd_nx = sd;
        if (t + 1 < tc) {
            const float* spn = sens + ((long)(t + 1) * BB + b) * (2 * NN);
            sn_nx = spn[j];
            sd_nx = spn[NN + j];
        }
#pragma unroll
        for (int u = 0; u < NUNFOLD; u++) {
            float pn0 = 0.f, pn1 = 0.f, pd0 = 0.f, pd1 = 0.f;
#pragma unroll
            for (int k = 0; k < 7; k++) {
                float vi = __int_as_float(
                    __builtin_amdgcn_ds_bpermute(src4[k], __float_as_int(v)));
                float tt = fmaf(sg2[k], vi, sb2[k]);
                float e  = __builtin_amdgcn_exp2f(tt);
                float sg = __builtin_amdgcn_rcpf(1.0f + e);
                if (k & 1) { pn1 = fmaf(Aa[k], sg, pn1); pd1 = fmaf(Wm[k], sg, pd1); }
                else       { pn0 = fmaf(Aa[k], sg, pn0); pd0 = fmaf(Wm[k], sg, pd0); }
            }
            float pn = pn0 + pn1;
            float pd = pd0 + pd1;
            // reduce over the 3 lanes of this j (leader at 3j reads 3j+1, 3j+2)
            float a1 = __int_as_float(__builtin_amdgcn_ds_bpermute(rp1, __float_as_int(pn)));
            float a2 = __int_as_float(__builtin_amdgcn_ds_bpermute(rp2, __float_as_int(pn)));
            float b1 = __int_as_float(__builtin_amdgcn_ds_bpermute(rp1, __float_as_int(pd)));
            float b2 = __int_as_float(__builtin_amdgcn_ds_bpermute(rp2, __float_as_int(pd)));
            pn = pn + a1 + a2;
            pd = pd + b1 + b2;
            float numer = fmaf(cmt, v, glvl) + pn + sn;
            float denom = cmt + gl + pd + sd + EPSV;
            float vn = numer * __builtin_amdgcn_rcpf(denom);
            v = leader ? vn : v;
        }
        if (lane == 0) outbuf[(long)b * TT + (t0 + t)] = fmaf(v, ow0, ob0);
        sn = sn_nx; sd = sd_nx;
    }
    if (leader) vstate[b * NN + j] = v;
}

// ---------------------------------------------------------------------------
// Phase 3: FC head.  One wave per (b, c).
// ---------------------------------------------------------------------------
__global__ void ltc_fc_kernel(const float* __restrict__ outbuf,
                              const float* __restrict__ fcw,
                              const float* __restrict__ fcb,
                              float* __restrict__ out)
{
    int bc = blockIdx.x;
    int b = bc / NCLASS;
    int c = bc % NCLASS;
    const float* xr = outbuf + (long)b * TT;
    const float* wr = fcw + (long)c * TT;
    float acc = 0.f;
    for (int t = threadIdx.x; t < TT; t += 64)
        acc = fmaf(xr[t], wr[t], acc);
#pragma unroll
    for (int off = 32; off > 0; off >>= 1)
        acc += __shfl_down(acc, off, 64);
    if (threadIdx.x == 0) out[bc] = acc + fcb[c];
}

// ---------------------------------------------------------------------------
extern "C" void kernel_launch(void* const* d_in, const int* in_sizes, int n_in,
                              void* d_out, int out_size, void* d_ws, size_t ws_size,
                              hipStream_t stream)
{
    const float* x     = (const float*)d_in[0];
    const float* iw    = (const float*)d_in[1];
    const float* ib    = (const float*)d_in[2];
    const float* smu   = (const float*)d_in[3];
    const float* ssig  = (const float*)d_in[4];
    const float* sw    = (const float*)d_in[5];
    const float* serev = (const float*)d_in[6];
    const float* mu    = (const float*)d_in[7];
    const float* sigma = (const float*)d_in[8];
    const float* w     = (const float*)d_in[9];
    const float* erev  = (const float*)d_in[10];
    const float* gleak = (const float*)d_in[11];
    const float* vleak = (const float*)d_in[12];
    const float* cm    = (const float*)d_in[13];
    const float* ow    = (const float*)d_in[14];
    const float* ob    = (const float*)d_in[15];
    const float* fcw   = (const float*)d_in[16];
    const float* fcb   = (const float*)d_in[17];
    const int* smask   = (const int*)d_in[18];
    const int* mask    = (const int*)d_in[19];
    float* out = (float*)d_out;

    // ws layout: [outbuf: B*T f32][vstate: B*N f32][sens: Tc*B*2N f32]
    float* outbuf = (float*)d_ws;
    float* vstate = outbuf + (long)BB * TT;
    float* sens   = vstate + (long)BB * NN;

    size_t fixed = ((size_t)BB * TT + (size_t)BB * NN) * sizeof(float);
    long avail = (long)ws_size - (long)fixed;
    long per_step = (long)BB * 2 * NN * sizeof(float);
    int Tc = (int)(avail / per_step);
    if (Tc > TT) Tc = TT;
    if (Tc < 1)  Tc = 1;   // assume ws is at least ~2.2 MB

    for (int t0 = 0; t0 < TT; t0 += Tc) {
        int tc = (TT - t0 < Tc) ? (TT - t0) : Tc;
        int total = tc * BB * NN;
        int blocks = (total + 255) / 256;
        ltc_sens_kernel<<<blocks, 256, 0, stream>>>(x, iw, ib, smu, ssig, sw,
                                                    serev, smask, sens, t0, tc);
        ltc_scan_kernel<<<BB, 64, 0, stream>>>(mu, sigma, w, erev, mask, gleak,
                                               vleak, cm, ow, ob, sens, outbuf,
                                               vstate, t0, tc, t0 == 0 ? 1 : 0);
    }
    ltc_fc_kernel<<<BB * NCLASS, 64, 0, stream>>>(outbuf, fcw, fcb, out);
}

// Round 2
// 3509.544 us; speedup vs baseline: 1.0489x; 1.0489x over previous
//
#include <hip/hip_runtime.h>

#define BB 256
#define TT 2048
#define SS 32
#define NN 19
#define NCLASS 10
#define NUNFOLD 6
#define EPSV 1e-8f
#define LOG2E 1.4426950408889634f

// ---------------------------------------------------------------------------
// Phase 1: sensory synapse precompute (input-only dependence, fully parallel).
// thread = (t, b, j): num/den over s=0..31 -> sens[t][b][0..18]=num, [19..37]=den
// ---------------------------------------------------------------------------
__global__ void ltc_sens_kernel(const float* __restrict__ x,
                                const float* __restrict__ iw,
                                const float* __restrict__ ib,
                                const float* __restrict__ smu,
                                const float* __restrict__ ssig,
                                const float* __restrict__ sw,
                                const float* __restrict__ serev,
                                const int* __restrict__ smask,
                                float* __restrict__ sens,
                                int t0, int tc)
{
    int gid = blockIdx.x * blockDim.x + threadIdx.x;
    int total = tc * BB * NN;
    if (gid >= total) return;
    int j  = gid % NN;
    int tb = gid / NN;
    int b  = tb % BB;
    int tl = tb / BB;
    int t  = t0 + tl;

    const float* xr = x + ((long)b * TT + t) * SS;
    float xin[SS];
    const float4* xr4 = (const float4*)xr;
#pragma unroll
    for (int q = 0; q < SS / 4; q++) {
        float4 v4 = xr4[q];
        xin[4 * q + 0] = v4.x; xin[4 * q + 1] = v4.y;
        xin[4 * q + 2] = v4.z; xin[4 * q + 3] = v4.w;
    }

    float num = 0.f, den = 0.f;
#pragma unroll
    for (int s = 0; s < SS; s++) {
        float inp = fmaf(xin[s], iw[s], ib[s]);
        int idx = s * NN + j;
        float sg = ssig[idx];
        float e  = __builtin_amdgcn_exp2f(fmaf(-LOG2E * sg, inp, LOG2E * sg * smu[idx]));
        float sig = __builtin_amdgcn_rcpf(1.0f + e);
        float wm = sw[idx] * (float)smask[idx] * sig;
        num = fmaf(wm, serev[idx], num);
        den += wm;
    }
    float* o = sens + ((long)tl * BB + b) * (2 * NN);
    o[j]      = num;
    o[NN + j] = den;
}

// ---------------------------------------------------------------------------
// DPP helper: lane l <- lane l+N within a 16-lane row (row_shl:N).
// ---------------------------------------------------------------------------
template <int CTRL>
__device__ __forceinline__ float dpp_shl(float x)
{
    return __int_as_float(__builtin_amdgcn_update_dpp(
        0, __float_as_int(x), CTRL, 0xf, 0xf, true));
}

// ---------------------------------------------------------------------------
// Phase 2: sequential scan.  One wave per batch element.
// Lane layout (DPP-friendly): lane = 16*(j/5) + 3*(j%5) + r, r=0..2.
// Lane 15 of each 16-row is a pad; triples never straddle a DPP row.
// r==0 covers pre-neurons [0,7), r==1 [7,13), r==2 [13,19).
// v broadcast: leader lanes -> SGPRs via v_readlane (no LDS round trip).
// 3-lane reduction: v_add + DPP row_shl:1 / row_shl:2 (no LDS round trip).
// ---------------------------------------------------------------------------
__global__ void __launch_bounds__(64, 1)
ltc_scan_kernel(const float* __restrict__ mu,  const float* __restrict__ sigma,
                const float* __restrict__ w,   const float* __restrict__ erev,
                const int* __restrict__ mask,
                const float* __restrict__ gleak, const float* __restrict__ vleak,
                const float* __restrict__ cm,
                const float* __restrict__ ow,  const float* __restrict__ ob,
                const float* __restrict__ sens, float* __restrict__ outbuf,
                float* __restrict__ vstate, int t0, int tc, int initv)
{
    int b    = blockIdx.x;
    int lane = threadIdx.x;
    int row  = lane >> 4;
    int pos  = lane & 15;
    int jq   = pos / 3;                 // 0..5 (5 => pad lane)
    int r    = pos - 3 * jq;
    int j    = row * 5 + jq;
    bool pad = (jq >= 5) || (j >= NN);
    int jc   = pad ? 0 : j;

    int i0  = (r == 0) ? 0 : (r == 1) ? 7 : 13;
    int cnt = pad ? 0 : ((r == 0) ? 7 : 6);

    // folded per-lane synapse constants
    float sg2[7], sb2[7], Aa[7], Wm[7];
#pragma unroll
    for (int k = 0; k < 7; k++) {
        bool ok = (k < cnt);
        int ii = ok ? (i0 + k) : 0;
        int idx = ii * NN + jc;
        float sg = sigma[idx];
        float wmm = ok ? (w[idx] * (float)mask[idx]) : 0.f;
        sg2[k] = -LOG2E * sg;
        sb2[k] = LOG2E * sg * mu[idx];
        Aa[k]  = wmm * erev[idx];
        Wm[k]  = wmm;
    }
    float cmt   = cm[jc] * (float)NUNFOLD;
    float gl    = gleak[jc];
    float glvl  = gl * vleak[jc];
    float cgl   = cmt + gl + EPSV;          // hoisted constant part of denom
    float ow0 = ow[0], ob0 = ob[0];

    bool is_r0 = (r == 0);
    bool is_r1 = (r == 1);

    float v = initv ? 0.f : vstate[b * NN + jc];

    const float* sp0 = sens + (long)b * (2 * NN);
    float sn = sp0[jc];
    float sd = sp0[NN + jc];

    for (int t = 0; t < tc; t++) {
        // prefetch next step's sensory sums (latency hidden by 6 unfolds)
        float sn_nx = sn, sd_nx = sd;
        if (t + 1 < tc) {
            const float* spn = sens + ((long)(t + 1) * BB + b) * (2 * NN);
            sn_nx = spn[jc];
            sd_nx = spn[NN + jc];
        }
        float nbase = glvl + sn;      // per-t, off critical path
        float dbase = cgl + sd;

#pragma unroll
        for (int u = 0; u < NUNFOLD; u++) {
            // broadcast leader v's to wave-uniform values (v_readlane, no LDS)
            float sv[19];
#pragma unroll
            for (int jj = 0; jj < NN; jj++) {
                const int Lj = (jj / 5) * 16 + (jj % 5) * 3;
                sv[jj] = __int_as_float(
                    __builtin_amdgcn_readlane(__float_as_int(v), Lj));
            }
            float numer_b = fmaf(cmt, v, nbase);   // early, off chain tail

            float pn0 = 0.f, pn1 = 0.f, pd0 = 0.f, pd1 = 0.f;
#pragma unroll
            for (int k = 0; k < 7; k++) {
                float vi;
                if (k < 6)
                    vi = is_r0 ? sv[k] : (is_r1 ? sv[7 + k] : sv[13 + k]);
                else
                    vi = sv[6];                     // only r==0 uses k==6
                float ttv = fmaf(sg2[k], vi, sb2[k]);
                float e   = __builtin_amdgcn_exp2f(ttv);
                float sg  = __builtin_amdgcn_rcpf(1.0f + e);
                if (k & 1) { pn1 = fmaf(Aa[k], sg, pn1); pd1 = fmaf(Wm[k], sg, pd1); }
                else       { pn0 = fmaf(Aa[k], sg, pn0); pd0 = fmaf(Wm[k], sg, pd0); }
            }
            float pn = pn0 + pn1;
            float pd = pd0 + pd1;
            // 3-lane reduction via DPP (leader at triple base gets the sum)
            pn = pn + dpp_shl<0x101>(pn) + dpp_shl<0x102>(pn);
            pd = pd + dpp_shl<0x101>(pd) + dpp_shl<0x102>(pd);

            float numer = numer_b + pn;
            float denom = dbase + pd;
            // all lanes update v; non-leader lanes hold garbage (never read:
            // readlane reads leaders only, DPP reduce reads pn/pd only)
            v = numer * __builtin_amdgcn_rcpf(denom);
        }
        if (lane == 0) outbuf[(long)b * TT + (t0 + t)] = fmaf(v, ow0, ob0);
        sn = sn_nx; sd = sd_nx;
    }
    if (!pad && r == 0) vstate[b * NN + j] = v;
}

// ---------------------------------------------------------------------------
// Phase 3: FC head.  One wave per (b, c).
// ---------------------------------------------------------------------------
__global__ void ltc_fc_kernel(const float* __restrict__ outbuf,
                              const float* __restrict__ fcw,
                              const float* __restrict__ fcb,
                              float* __restrict__ out)
{
    int bc = blockIdx.x;
    int b = bc / NCLASS;
    int c = bc % NCLASS;
    const float* xr = outbuf + (long)b * TT;
    const float* wr = fcw + (long)c * TT;
    float acc = 0.f;
    for (int t = threadIdx.x; t < TT; t += 64)
        acc = fmaf(xr[t], wr[t], acc);
#pragma unroll
    for (int off = 32; off > 0; off >>= 1)
        acc += __shfl_down(acc, off, 64);
    if (threadIdx.x == 0) out[bc] = acc + fcb[c];
}

// ---------------------------------------------------------------------------
extern "C" void kernel_launch(void* const* d_in, const int* in_sizes, int n_in,
                              void* d_out, int out_size, void* d_ws, size_t ws_size,
                              hipStream_t stream)
{
    const float* x     = (const float*)d_in[0];
    const float* iw    = (const float*)d_in[1];
    const float* ib    = (const float*)d_in[2];
    const float* smu   = (const float*)d_in[3];
    const float* ssig  = (const float*)d_in[4];
    const float* sw    = (const float*)d_in[5];
    const float* serev = (const float*)d_in[6];
    const float* mu    = (const float*)d_in[7];
    const float* sigma = (const float*)d_in[8];
    const float* w     = (const float*)d_in[9];
    const float* erev  = (const float*)d_in[10];
    const float* gleak = (const float*)d_in[11];
    const float* vleak = (const float*)d_in[12];
    const float* cm    = (const float*)d_in[13];
    const float* ow    = (const float*)d_in[14];
    const float* ob    = (const float*)d_in[15];
    const float* fcw   = (const float*)d_in[16];
    const float* fcb   = (const float*)d_in[17];
    const int* smask   = (const int*)d_in[18];
    const int* mask    = (const int*)d_in[19];
    float* out = (float*)d_out;

    // ws layout: [outbuf: B*T f32][vstate: B*N f32][sens: Tc*B*2N f32]
    float* outbuf = (float*)d_ws;
    float* vstate = outbuf + (long)BB * TT;
    float* sens   = vstate + (long)BB * NN;

    size_t fixed = ((size_t)BB * TT + (size_t)BB * NN) * sizeof(float);
    long avail = (long)ws_size - (long)fixed;
    long per_step = (long)BB * 2 * NN * sizeof(float);
    int Tc = (int)(avail / per_step);
    if (Tc > TT) Tc = TT;
    if (Tc < 1)  Tc = 1;

    for (int t0 = 0; t0 < TT; t0 += Tc) {
        int tc = (TT - t0 < Tc) ? (TT - t0) : Tc;
        int total = tc * BB * NN;
        int blocks = (total + 255) / 256;
        ltc_sens_kernel<<<blocks, 256, 0, stream>>>(x, iw, ib, smu, ssig, sw,
                                                    serev, smask, sens, t0, tc);
        ltc_scan_kernel<<<BB, 64, 0, stream>>>(mu, sigma, w, erev, mask, gleak,
                                               vleak, cm, ow, ob, sens, outbuf,
                                               vstate, t0, tc, t0 == 0 ? 1 : 0);
    }
    ltc_fc_kernel<<<BB * NCLASS, 64, 0, stream>>>(outbuf, fcw, fcb, out);
}